// Round 2
// baseline (634.383 us; speedup 1.0000x reference)
//
#include <hip/hip_runtime.h>

typedef unsigned short ushort_t;
typedef float f32x4 __attribute__((ext_vector_type(4)));
typedef __bf16 bf16x8 __attribute__((ext_vector_type(8)));
typedef short s16x8 __attribute__((ext_vector_type(8)));

#define NB 8
#define QL 256
#define HID 4096
#define NH 32
#define HD 128

__device__ __forceinline__ float b2f(ushort_t u) {
  union { unsigned int i; float f; } x; x.i = ((unsigned int)u) << 16; return x.f;
}
__device__ __forceinline__ ushort_t f2b(float f) {
  union { float f; unsigned int i; } x; x.f = f;
  unsigned int r = (x.i + 0x7fffu + ((x.i >> 16) & 1u)) >> 16;
  return (ushort_t)r;
}

#define MFMA16(a, b, c) __builtin_amdgcn_mfma_f32_16x16x32_bf16((a), (b), (c), 0, 0, 0)

// ---------------------------------------------------------------------------
// fp32 -> bf16 convert (n8 = n/8 groups of 8)
// ---------------------------------------------------------------------------
__global__ __launch_bounds__(256)
void conv_bf16(const float* __restrict__ s, ushort_t* __restrict__ d, int n8) {
  for (int i = blockIdx.x * blockDim.x + threadIdx.x; i < n8;
       i += gridDim.x * blockDim.x) {
    const float* sp = s + (size_t)i * 8;
    ushort_t t[8];
#pragma unroll
    for (int j = 0; j < 8; ++j) t[j] = f2b(sp[j]);
    *(s16x8*)(d + (size_t)i * 8) = *(s16x8*)t;
  }
}

// fp32 -> (hi bf16, lo bf16) split: v = hi + lo to ~16-bit mantissa
__global__ __launch_bounds__(256)
void conv_split(const float* __restrict__ s, ushort_t* __restrict__ hi,
                ushort_t* __restrict__ lo, int n8) {
  for (int i = blockIdx.x * blockDim.x + threadIdx.x; i < n8;
       i += gridDim.x * blockDim.x) {
    const float* sp = s + (size_t)i * 8;
    ushort_t th[8], tl[8];
#pragma unroll
    for (int j = 0; j < 8; ++j) {
      const float v = sp[j];
      const ushort_t h = f2b(v);
      th[j] = h;
      tl[j] = f2b(v - b2f(h));
    }
    *(s16x8*)(hi + (size_t)i * 8) = *(s16x8*)th;
    *(s16x8*)(lo + (size_t)i * 8) = *(s16x8*)tl;
  }
}

// ---------------------------------------------------------------------------
// GEMM (bf16 in, bf16 out): C[M][N] = A[M][K] * B[N][K]^T (+bias_f32[n]).
// 128x128 tile, BK=32, 256 threads (4 waves 2x2), global_load_lds staging.
// ---------------------------------------------------------------------------
__global__ __launch_bounds__(256, 3)
void gemm_bt_qkv(const ushort_t* __restrict__ A, const ushort_t* __restrict__ Bm,
                 const float* __restrict__ bias, ushort_t* __restrict__ C,
                 int M, int N, int K) {
  __shared__ ushort_t As[128 * 32];
  __shared__ ushort_t Bs[128 * 32];
  const int tid = threadIdx.x;
  const int w = tid >> 6, l = tid & 63;
  const int l16 = l & 15, lg = l >> 4;
  const int wr = w >> 1, wc = w & 1;
  const int tile_m = blockIdx.y * 128;
  const int tile_n = blockIdx.x * 128;

  f32x4 acc[4][4];
#pragma unroll
  for (int m = 0; m < 4; ++m)
#pragma unroll
    for (int n = 0; n < 4; ++n) acc[m][n] = (f32x4){0.f, 0.f, 0.f, 0.f};

  const int lrow = l >> 2;
  const int lseg = l & 3;
  const size_t a_base = (size_t)(tile_m + (w * 2) * 16 + lrow) * K + lseg * 8;
  const size_t b_base = (size_t)(tile_n + (w * 2) * 16 + lrow) * K + lseg * 8;

  for (int kt = 0; kt < K; kt += 32) {
#pragma unroll
    for (int i = 0; i < 2; ++i) {
      const int chunk = w * 2 + i;
      const ushort_t* ga = A + a_base + (size_t)i * 16 * K + kt;
      const ushort_t* gb = Bm + b_base + (size_t)i * 16 * K + kt;
      __builtin_amdgcn_global_load_lds(
          (const __attribute__((address_space(1))) void*)ga,
          (__attribute__((address_space(3))) void*)&As[chunk * 512], 16, 0, 0);
      __builtin_amdgcn_global_load_lds(
          (const __attribute__((address_space(1))) void*)gb,
          (__attribute__((address_space(3))) void*)&Bs[chunk * 512], 16, 0, 0);
    }
    __syncthreads();

    bf16x8 af[4], bfr[4];
#pragma unroll
    for (int m = 0; m < 4; ++m)
      af[m] = *(const bf16x8*)&As[(wr * 64 + m * 16 + l16) * 32 + lg * 8];
#pragma unroll
    for (int n = 0; n < 4; ++n)
      bfr[n] = *(const bf16x8*)&Bs[(wc * 64 + n * 16 + l16) * 32 + lg * 8];
#pragma unroll
    for (int m = 0; m < 4; ++m)
#pragma unroll
      for (int n = 0; n < 4; ++n)
        acc[m][n] = MFMA16(af[m], bfr[n], acc[m][n]);
    __syncthreads();
  }

#pragma unroll
  for (int n = 0; n < 4; ++n) {
    const int col = tile_n + wc * 64 + n * 16 + l16;
    const float bi = bias[col];
#pragma unroll
    for (int m = 0; m < 4; ++m) {
      const int row0 = tile_m + wr * 64 + m * 16 + lg * 4;
#pragma unroll
      for (int r = 0; r < 4; ++r)
        C[(size_t)(row0 + r) * N + col] = f2b(acc[m][n][r] + bi);
    }
  }
}

// ---------------------------------------------------------------------------
// Split GEMM (fp32-quality): C_f32 = (Ah+Al)(Bh+Bl)^T ~= AhBh + AhBl + AlBh
// ---------------------------------------------------------------------------
__global__ __launch_bounds__(256, 2)
void gemm_split(const ushort_t* __restrict__ Ah, const ushort_t* __restrict__ Al,
                const ushort_t* __restrict__ Bh, const ushort_t* __restrict__ Bl,
                float* __restrict__ C, int M, int N, int K) {
  __shared__ ushort_t Ash[128 * 32];
  __shared__ ushort_t Asl[128 * 32];
  __shared__ ushort_t Bsh[128 * 32];
  __shared__ ushort_t Bsl[128 * 32];
  const int tid = threadIdx.x;
  const int w = tid >> 6, l = tid & 63;
  const int l16 = l & 15, lg = l >> 4;
  const int wr = w >> 1, wc = w & 1;
  const int tile_m = blockIdx.y * 128;
  const int tile_n = blockIdx.x * 128;

  f32x4 acc[4][4];
#pragma unroll
  for (int m = 0; m < 4; ++m)
#pragma unroll
    for (int n = 0; n < 4; ++n) acc[m][n] = (f32x4){0.f, 0.f, 0.f, 0.f};

  const int lrow = l >> 2;
  const int lseg = l & 3;
  const size_t a_base = (size_t)(tile_m + (w * 2) * 16 + lrow) * K + lseg * 8;
  const size_t b_base = (size_t)(tile_n + (w * 2) * 16 + lrow) * K + lseg * 8;

  for (int kt = 0; kt < K; kt += 32) {
#pragma unroll
    for (int i = 0; i < 2; ++i) {
      const int chunk = w * 2 + i;
      const size_t ao = a_base + (size_t)i * 16 * K + kt;
      const size_t bo = b_base + (size_t)i * 16 * K + kt;
      __builtin_amdgcn_global_load_lds(
          (const __attribute__((address_space(1))) void*)(Ah + ao),
          (__attribute__((address_space(3))) void*)&Ash[chunk * 512], 16, 0, 0);
      __builtin_amdgcn_global_load_lds(
          (const __attribute__((address_space(1))) void*)(Al + ao),
          (__attribute__((address_space(3))) void*)&Asl[chunk * 512], 16, 0, 0);
      __builtin_amdgcn_global_load_lds(
          (const __attribute__((address_space(1))) void*)(Bh + bo),
          (__attribute__((address_space(3))) void*)&Bsh[chunk * 512], 16, 0, 0);
      __builtin_amdgcn_global_load_lds(
          (const __attribute__((address_space(1))) void*)(Bl + bo),
          (__attribute__((address_space(3))) void*)&Bsl[chunk * 512], 16, 0, 0);
    }
    __syncthreads();

    bf16x8 afh[4], afl[4], bfh[4], bfl[4];
#pragma unroll
    for (int m = 0; m < 4; ++m) {
      const int off = (wr * 64 + m * 16 + l16) * 32 + lg * 8;
      afh[m] = *(const bf16x8*)&Ash[off];
      afl[m] = *(const bf16x8*)&Asl[off];
    }
#pragma unroll
    for (int n = 0; n < 4; ++n) {
      const int off = (wc * 64 + n * 16 + l16) * 32 + lg * 8;
      bfh[n] = *(const bf16x8*)&Bsh[off];
      bfl[n] = *(const bf16x8*)&Bsl[off];
    }
#pragma unroll
    for (int m = 0; m < 4; ++m)
#pragma unroll
      for (int n = 0; n < 4; ++n) {
        acc[m][n] = MFMA16(afh[m], bfh[n], acc[m][n]);
        acc[m][n] = MFMA16(afh[m], bfl[n], acc[m][n]);
        acc[m][n] = MFMA16(afl[m], bfh[n], acc[m][n]);
      }
    __syncthreads();
  }

#pragma unroll
  for (int n = 0; n < 4; ++n) {
    const int col = tile_n + wc * 64 + n * 16 + l16;
#pragma unroll
    for (int m = 0; m < 4; ++m) {
      const int row0 = tile_m + wr * 64 + m * 16 + lg * 4;
#pragma unroll
      for (int r = 0; r < 4; ++r)
        C[(size_t)(row0 + r) * N + col] = acc[m][n][r];
    }
  }
}

// ---------------------------------------------------------------------------
// RoPE + qkv split (bf16 in/out). q gets 1/sqrt(HD) folded in.
// ---------------------------------------------------------------------------
__global__ __launch_bounds__(256)
void rope_split(const ushort_t* __restrict__ qkv, const int* __restrict__ hist,
                ushort_t* __restrict__ q_r, ushort_t* __restrict__ k_r,
                ushort_t* __restrict__ v_r) {
  const int t = blockIdx.x;
  const int b = t >> 8, qq = t & 255;
  __shared__ float cs[64], sn[64];
  const int tid = threadIdx.x;
  if (tid < 64) {
    const float pos = (float)(hist[b] + qq);
    const float f = pos * __expf(-(float)tid * (9.210340371976184f / 64.0f));
    cs[tid] = cosf(f);
    sn[tid] = sinf(f);
  }
  __syncthreads();
  const ushort_t* src = qkv + (size_t)t * 12288;
  const float qscale = 0.08838834764831845f;
  for (int i = tid; i < NH * 64; i += 256) {
    const int h = i >> 6, j = i & 63;
    const float c = cs[j], s = sn[j];
    const size_t dst = ((size_t)(b * NH + h) * QL + qq) * HD;
    {
      const float x1 = b2f(src[h * HD + j]);
      const float x2 = b2f(src[h * HD + j + 64]);
      q_r[dst + j]      = f2b((x1 * c - x2 * s) * qscale);
      q_r[dst + j + 64] = f2b((x2 * c + x1 * s) * qscale);
    }
    {
      const float x1 = b2f(src[HID + h * HD + j]);
      const float x2 = b2f(src[HID + h * HD + j + 64]);
      k_r[dst + j]      = f2b(x1 * c - x2 * s);
      k_r[dst + j + 64] = f2b(x2 * c + x1 * s);
    }
    v_r[dst + j]      = src[2 * HID + h * HD + j];
    v_r[dst + j + 64] = src[2 * HID + h * HD + j + 64];
  }
}

// ---------------------------------------------------------------------------
// Flash attention over paged KV (caches are fp32; fresh K/V are bf16).
// One block per (b,h): 512 threads = 8 waves, each wave 32 q rows.
// Output: attn split to hi/lo bf16 for the split proj GEMM.
// ---------------------------------------------------------------------------
__global__ __launch_bounds__(512, 2)
void attn_fwd(const ushort_t* __restrict__ q_r, const ushort_t* __restrict__ k_r,
              const ushort_t* __restrict__ v_r,
              const float* __restrict__ k_cache, const float* __restrict__ v_cache,
              const int* __restrict__ hist, const int* __restrict__ bofs,
              ushort_t* __restrict__ attn_hi, ushort_t* __restrict__ attn_lo) {
  const int bh = blockIdx.x;
  const int b = bh >> 5, h = bh & 31;
  const int hb = hist[b];

  __shared__ ushort_t K_lds[64 * 136];
  __shared__ ushort_t V_lds[128 * 72];
  __shared__ ushort_t P_lds[256 * 72];

  const int tid = threadIdx.x;
  const int w = tid >> 6, l = tid & 63;
  const int l16 = l & 15, lg = l >> 4;

  bf16x8 qf[2][4];
#pragma unroll
  for (int m = 0; m < 2; ++m) {
    const int qrow = w * 32 + m * 16 + l16;
    const ushort_t* qp = q_r + ((size_t)(b * NH + h) * QL + qrow) * HD + lg * 8;
#pragma unroll
    for (int kd = 0; kd < 4; ++kd) qf[m][kd] = *(const bf16x8*)(qp + kd * 32);
  }

  f32x4 o[2][8];
  float mr[2][4], sr[2][4];
#pragma unroll
  for (int m = 0; m < 2; ++m) {
#pragma unroll
    for (int d = 0; d < 8; ++d) o[m][d] = (f32x4){0.f, 0.f, 0.f, 0.f};
#pragma unroll
    for (int r = 0; r < 4; ++r) { mr[m][r] = -1e30f; sr[m][r] = 0.f; }
  }

  const int nt = (hb + QL + 63) >> 6;
  const int srow = tid >> 4;
  const int seg = tid & 15;

  for (int t = 0; t < nt; ++t) {
    const int kv0 = t << 6;
    __syncthreads();
#pragma unroll
    for (int p = 0; p < 2; ++p) {
      const int row = p * 32 + srow;
      const int kvg = kv0 + row;
      if (kvg < hb) {
        const int blk = bofs[b * 12 + t];
        const size_t base = ((size_t)blk * 64 + (kvg & 63)) * HID + h * HD;
        const float* kf = k_cache + base;
        const float* vf = v_cache + base;
        ushort_t tmp[8];
#pragma unroll
        for (int j = 0; j < 8; ++j) tmp[j] = f2b(kf[seg * 8 + j]);
        *(s16x8*)&K_lds[row * 136 + seg * 8] = *(s16x8*)tmp;
#pragma unroll
        for (int j = 0; j < 8; ++j) {
          const int d = seg + j * 16;
          V_lds[d * 72 + row] = f2b(vf[d]);
        }
      } else {
        int r2 = kvg - hb;
        if (r2 > QL - 1) r2 = QL - 1;
        const size_t base = ((size_t)(b * NH + h) * QL + r2) * HD;
        const ushort_t* kb = k_r + base;
        const ushort_t* vb = v_r + base;
        *(s16x8*)&K_lds[row * 136 + seg * 8] = *(const s16x8*)(kb + seg * 8);
#pragma unroll
        for (int j = 0; j < 8; ++j) {
          const int d = seg + j * 16;
          V_lds[d * 72 + row] = vb[d];
        }
      }
    }
    __syncthreads();

    f32x4 sa[2][4];
#pragma unroll
    for (int m = 0; m < 2; ++m)
#pragma unroll
      for (int n = 0; n < 4; ++n) sa[m][n] = (f32x4){0.f, 0.f, 0.f, 0.f};
#pragma unroll
    for (int kd = 0; kd < 4; ++kd) {
      bf16x8 kf[4];
#pragma unroll
      for (int n = 0; n < 4; ++n)
        kf[n] = *(const bf16x8*)&K_lds[(n * 16 + l16) * 136 + kd * 32 + lg * 8];
#pragma unroll
      for (int m = 0; m < 2; ++m)
#pragma unroll
        for (int n = 0; n < 4; ++n)
          sa[m][n] = MFMA16(qf[m][kd], kf[n], sa[m][n]);
    }

#pragma unroll
    for (int m = 0; m < 2; ++m) {
#pragma unroll
      for (int n = 0; n < 4; ++n) {
        const int kvg = kv0 + n * 16 + l16;
#pragma unroll
        for (int r = 0; r < 4; ++r) {
          const int qg = hb + w * 32 + m * 16 + lg * 4 + r;
          if (kvg > qg) sa[m][n][r] = -1e30f;
        }
      }
      float tm[4], ts[4];
#pragma unroll
      for (int r = 0; r < 4; ++r)
        tm[r] = fmaxf(fmaxf(sa[m][0][r], sa[m][1][r]),
                      fmaxf(sa[m][2][r], sa[m][3][r]));
#pragma unroll
      for (int x = 1; x < 16; x <<= 1)
#pragma unroll
        for (int r = 0; r < 4; ++r)
          tm[r] = fmaxf(tm[r], __shfl_xor(tm[r], x, 16));
#pragma unroll
      for (int r = 0; r < 4; ++r) {
        const float nm = fmaxf(mr[m][r], tm[r]);
        const float corr = __expf(mr[m][r] - nm);
        mr[m][r] = nm;
        sr[m][r] *= corr;
#pragma unroll
        for (int d = 0; d < 8; ++d) o[m][d][r] *= corr;
        ts[r] = 0.f;
      }
#pragma unroll
      for (int n = 0; n < 4; ++n)
#pragma unroll
        for (int r = 0; r < 4; ++r) {
          const float p = __expf(sa[m][n][r] - mr[m][r]);
          sa[m][n][r] = p;
          ts[r] += p;
        }
#pragma unroll
      for (int x = 1; x < 16; x <<= 1)
#pragma unroll
        for (int r = 0; r < 4; ++r) ts[r] += __shfl_xor(ts[r], x, 16);
#pragma unroll
      for (int r = 0; r < 4; ++r) sr[m][r] += ts[r];
#pragma unroll
      for (int n = 0; n < 4; ++n)
#pragma unroll
        for (int r = 0; r < 4; ++r)
          P_lds[(w * 32 + m * 16 + lg * 4 + r) * 72 + n * 16 + l16] =
              f2b(sa[m][n][r]);
    }

#pragma unroll
    for (int ks = 0; ks < 2; ++ks) {
      bf16x8 pa[2];
#pragma unroll
      for (int m = 0; m < 2; ++m)
        pa[m] = *(const bf16x8*)&P_lds[(w * 32 + m * 16 + l16) * 72 + ks * 32 + lg * 8];
#pragma unroll
      for (int d = 0; d < 8; ++d) {
        const bf16x8 vb =
            *(const bf16x8*)&V_lds[(d * 16 + l16) * 72 + ks * 32 + lg * 8];
#pragma unroll
        for (int m = 0; m < 2; ++m) o[m][d] = MFMA16(pa[m], vb, o[m][d]);
      }
    }
  }

#pragma unroll
  for (int m = 0; m < 2; ++m)
#pragma unroll
    for (int r = 0; r < 4; ++r) {
      const int qrow = w * 32 + m * 16 + lg * 4 + r;
      const float inv = 1.0f / sr[m][r];
      const size_t obase = ((size_t)(b * QL + qrow)) * HID + h * HD;
#pragma unroll
      for (int d = 0; d < 8; ++d) {
        const float val = o[m][d][r] * inv;
        const ushort_t hi = f2b(val);
        attn_hi[obase + d * 16 + l16] = hi;
        attn_lo[obase + d * 16 + l16] = f2b(val - b2f(hi));
      }
    }
}

// ---------------------------------------------------------------------------
extern "C" void kernel_launch(void* const* d_in, const int* in_sizes, int n_in,
                              void* d_out, int out_size, void* d_ws,
                              size_t ws_size, hipStream_t stream) {
  const float* hidden   = (const float*)d_in[0];  // (1,2048,4096) f32
  const float* c_attn_w = (const float*)d_in[1];  // (12288,4096)
  const float* c_attn_b = (const float*)d_in[2];  // (12288,)
  const float* c_proj_w = (const float*)d_in[3];  // (4096,4096)
  const float* k_cache  = (const float*)d_in[4];  // (96,64,32,128)
  const float* v_cache  = (const float*)d_in[5];
  const int* hist       = (const int*)d_in[6];    // (8,)
  const int* bofs       = (const int*)d_in[7];    // (8,12)
  float* out = (float*)d_out;

  char* ws = (char*)d_ws;
  const size_t MB = 1ull << 20;
  // Region A (0..96MB): w_attn_bf (phase 1) -> wproj_hi/lo (phase 4+)
  ushort_t* w_attn_bf = (ushort_t*)(ws);
  ushort_t* wproj_hi  = (ushort_t*)(ws);
  ushort_t* wproj_lo  = (ushort_t*)(ws + 32 * MB);
  // Region B (100..148MB): qkv_bf (phases 1-2) -> attn_hi/lo (phase 5+)
  ushort_t* qkv_bf  = (ushort_t*)(ws + 100 * MB);
  ushort_t* attn_hi = (ushort_t*)(ws + 100 * MB);
  ushort_t* attn_lo = (ushort_t*)(ws + 116 * MB);
  // Region C: roped q/k/v
  ushort_t* q_r = (ushort_t*)(ws + 148 * MB);
  ushort_t* k_r = (ushort_t*)(ws + 164 * MB);
  ushort_t* v_r = (ushort_t*)(ws + 180 * MB);
  // Region D: x_bf
  ushort_t* x_bf = (ushort_t*)(ws + 196 * MB);

  // 1) convert inputs for qkv GEMM
  conv_bf16<<<2048, 256, 0, stream>>>(hidden, x_bf, 2048 * 4096 / 8);
  conv_bf16<<<2048, 256, 0, stream>>>(c_attn_w, w_attn_bf, 12288 * 4096 / 8);
  // 2) qkv = x @ c_attn_w^T + b  (bf16 MFMA, fp32 accum)
  gemm_bt_qkv<<<dim3(96, 16), dim3(256), 0, stream>>>(
      x_bf, w_attn_bf, c_attn_b, qkv_bf, 2048, 12288, 4096);
  // 3) rope + split
  rope_split<<<dim3(2048), dim3(256), 0, stream>>>(qkv_bf, hist, q_r, k_r, v_r);
  // 4) split-convert proj weights (overwrites w_attn_bf region; stream-ordered)
  conv_split<<<2048, 256, 0, stream>>>(c_proj_w, wproj_hi, wproj_lo,
                                       4096 * 4096 / 8);
  // 5) attention -> attn hi/lo (overwrites qkv region; qkv dead after rope)
  attn_fwd<<<dim3(256), dim3(512), 0, stream>>>(
      q_r, k_r, v_r, k_cache, v_cache, hist, bofs, attn_hi, attn_lo);
  // 6) out = attn @ c_proj_w^T in split-bf16 (~fp32 quality)
  gemm_split<<<dim3(32, 16), dim3(256), 0, stream>>>(
      attn_hi, attn_lo, wproj_hi, wproj_lo, out, 2048, 4096, 4096);
}

// Round 3
// 549.444 us; speedup vs baseline: 1.1546x; 1.1546x over previous
//
#include <hip/hip_runtime.h>

typedef unsigned short ushort_t;
typedef float f32x4 __attribute__((ext_vector_type(4)));
typedef _Float16 f16x8 __attribute__((ext_vector_type(8)));
typedef short s16x8 __attribute__((ext_vector_type(8)));

#define NB 8
#define QL 256
#define HID 4096
#define NH 32
#define HD 128

__device__ __forceinline__ _Float16 f2h(float f) { return (_Float16)f; }
__device__ __forceinline__ ushort_t h2u(_Float16 h) {
  union { _Float16 h; ushort_t u; } x; x.h = h; return x.u;
}
__device__ __forceinline__ float u2f(ushort_t u) {
  union { _Float16 h; ushort_t u; } x; x.u = u; return (float)x.h;
}

#define MFMA16H(a, b, c) __builtin_amdgcn_mfma_f32_16x16x32_f16((a), (b), (c), 0, 0, 0)

// ---------------------------------------------------------------------------
// fp32 -> fp16 convert (n8 = n/8 groups of 8)
// ---------------------------------------------------------------------------
__global__ __launch_bounds__(256)
void conv_h(const float* __restrict__ s, ushort_t* __restrict__ d, int n8) {
  for (int i = blockIdx.x * blockDim.x + threadIdx.x; i < n8;
       i += gridDim.x * blockDim.x) {
    const float* sp = s + (size_t)i * 8;
    ushort_t t[8];
#pragma unroll
    for (int j = 0; j < 8; ++j) t[j] = h2u(f2h(sp[j]));
    *(s16x8*)(d + (size_t)i * 8) = *(s16x8*)t;
  }
}

// ---------------------------------------------------------------------------
// GEMM (fp16 in): C[M][N] = A[M][K] * B[N][K]^T (+bias_f32[n]).
// 128x128 tile, BK=32, 256 threads (4 waves 2x2), global_load_lds staging.
// 1D grid with XCD-aware swizzle (T1); M-tiles fixed at 16 (M=2048).
// OUT_F32: write float C, else fp16 (ushort).
// ---------------------------------------------------------------------------
template<int ADD_BIAS, int OUT_F32>
__global__ __launch_bounds__(256, 3)
void gemm_bt(const ushort_t* __restrict__ A, const ushort_t* __restrict__ Bm,
             const float* __restrict__ bias, ushort_t* __restrict__ Ch,
             float* __restrict__ Cf, int N, int K) {
  // T1: bijective XCD swizzle (nwg % 8 == 0), consecutive wg share B-panel
  const int nwg = gridDim.x;
  const int bid = blockIdx.x;
  const int wg = (bid & 7) * (nwg >> 3) + (bid >> 3);
  const int tile_m = (wg & 15) * 128;
  const int tile_n = (wg >> 4) * 128;

  __shared__ ushort_t As[128 * 32];
  __shared__ ushort_t Bs[128 * 32];
  const int tid = threadIdx.x;
  const int w = tid >> 6, l = tid & 63;
  const int l16 = l & 15, lg = l >> 4;
  const int wr = w >> 1, wc = w & 1;

  f32x4 acc[4][4];
#pragma unroll
  for (int m = 0; m < 4; ++m)
#pragma unroll
    for (int n = 0; n < 4; ++n) acc[m][n] = (f32x4){0.f, 0.f, 0.f, 0.f};

  const int lrow = l >> 2;
  const int lseg = l & 3;
  const size_t a_base = (size_t)(tile_m + (w * 2) * 16 + lrow) * K + lseg * 8;
  const size_t b_base = (size_t)(tile_n + (w * 2) * 16 + lrow) * K + lseg * 8;

  for (int kt = 0; kt < K; kt += 32) {
#pragma unroll
    for (int i = 0; i < 2; ++i) {
      const int chunk = w * 2 + i;
      const ushort_t* ga = A + a_base + (size_t)i * 16 * K + kt;
      const ushort_t* gb = Bm + b_base + (size_t)i * 16 * K + kt;
      __builtin_amdgcn_global_load_lds(
          (const __attribute__((address_space(1))) void*)ga,
          (__attribute__((address_space(3))) void*)&As[chunk * 512], 16, 0, 0);
      __builtin_amdgcn_global_load_lds(
          (const __attribute__((address_space(1))) void*)gb,
          (__attribute__((address_space(3))) void*)&Bs[chunk * 512], 16, 0, 0);
    }
    __syncthreads();

    f16x8 af[4], bfr[4];
#pragma unroll
    for (int m = 0; m < 4; ++m)
      af[m] = *(const f16x8*)&As[(wr * 64 + m * 16 + l16) * 32 + lg * 8];
#pragma unroll
    for (int n = 0; n < 4; ++n)
      bfr[n] = *(const f16x8*)&Bs[(wc * 64 + n * 16 + l16) * 32 + lg * 8];
#pragma unroll
    for (int m = 0; m < 4; ++m)
#pragma unroll
      for (int n = 0; n < 4; ++n)
        acc[m][n] = MFMA16H(af[m], bfr[n], acc[m][n]);
    __syncthreads();
  }

#pragma unroll
  for (int n = 0; n < 4; ++n) {
    const int col = tile_n + wc * 64 + n * 16 + l16;
    const float bi = ADD_BIAS ? bias[col] : 0.0f;
#pragma unroll
    for (int m = 0; m < 4; ++m) {
      const int row0 = tile_m + wr * 64 + m * 16 + lg * 4;
#pragma unroll
      for (int r = 0; r < 4; ++r) {
        if (OUT_F32)
          Cf[(size_t)(row0 + r) * N + col] = acc[m][n][r] + bi;
        else
          Ch[(size_t)(row0 + r) * N + col] = h2u(f2h(acc[m][n][r] + bi));
      }
    }
  }
}

// ---------------------------------------------------------------------------
// RoPE + qkv split (fp16 in/out). q gets 1/sqrt(HD) folded in.
// ---------------------------------------------------------------------------
__global__ __launch_bounds__(256)
void rope_split(const ushort_t* __restrict__ qkv, const int* __restrict__ hist,
                ushort_t* __restrict__ q_r, ushort_t* __restrict__ k_r,
                ushort_t* __restrict__ v_r) {
  const int t = blockIdx.x;
  const int b = t >> 8, qq = t & 255;
  __shared__ float cs[64], sn[64];
  const int tid = threadIdx.x;
  if (tid < 64) {
    const float pos = (float)(hist[b] + qq);
    const float f = pos * __expf(-(float)tid * (9.210340371976184f / 64.0f));
    cs[tid] = cosf(f);
    sn[tid] = sinf(f);
  }
  __syncthreads();
  const ushort_t* src = qkv + (size_t)t * 12288;
  const float qscale = 0.08838834764831845f;
  for (int i = tid; i < NH * 64; i += 256) {
    const int h = i >> 6, j = i & 63;
    const float c = cs[j], s = sn[j];
    const size_t dst = ((size_t)(b * NH + h) * QL + qq) * HD;
    {
      const float x1 = u2f(src[h * HD + j]);
      const float x2 = u2f(src[h * HD + j + 64]);
      q_r[dst + j]      = h2u(f2h((x1 * c - x2 * s) * qscale));
      q_r[dst + j + 64] = h2u(f2h((x2 * c + x1 * s) * qscale));
    }
    {
      const float x1 = u2f(src[HID + h * HD + j]);
      const float x2 = u2f(src[HID + h * HD + j + 64]);
      k_r[dst + j]      = h2u(f2h(x1 * c - x2 * s));
      k_r[dst + j + 64] = h2u(f2h(x2 * c + x1 * s));
    }
    v_r[dst + j]      = src[2 * HID + h * HD + j];
    v_r[dst + j + 64] = src[2 * HID + h * HD + j + 64];
  }
}

// ---------------------------------------------------------------------------
// Flash attention over paged KV (caches fp32; fresh K/V fp16).
// One block per (b,h): 512 threads = 8 waves, each wave 32 q rows.
// Output: fp16 attn (T, HID).
// ---------------------------------------------------------------------------
__global__ __launch_bounds__(512, 2)
void attn_fwd(const ushort_t* __restrict__ q_r, const ushort_t* __restrict__ k_r,
              const ushort_t* __restrict__ v_r,
              const float* __restrict__ k_cache, const float* __restrict__ v_cache,
              const int* __restrict__ hist, const int* __restrict__ bofs,
              ushort_t* __restrict__ attn_h) {
  const int bh = blockIdx.x;
  const int b = bh >> 5, h = bh & 31;
  const int hb = hist[b];

  __shared__ ushort_t K_lds[64 * 136];
  __shared__ ushort_t V_lds[128 * 72];
  __shared__ ushort_t P_lds[256 * 72];

  const int tid = threadIdx.x;
  const int w = tid >> 6, l = tid & 63;
  const int l16 = l & 15, lg = l >> 4;

  f16x8 qf[2][4];
#pragma unroll
  for (int m = 0; m < 2; ++m) {
    const int qrow = w * 32 + m * 16 + l16;
    const ushort_t* qp = q_r + ((size_t)(b * NH + h) * QL + qrow) * HD + lg * 8;
#pragma unroll
    for (int kd = 0; kd < 4; ++kd) qf[m][kd] = *(const f16x8*)(qp + kd * 32);
  }

  f32x4 o[2][8];
  float mr[2][4], sr[2][4];
#pragma unroll
  for (int m = 0; m < 2; ++m) {
#pragma unroll
    for (int d = 0; d < 8; ++d) o[m][d] = (f32x4){0.f, 0.f, 0.f, 0.f};
#pragma unroll
    for (int r = 0; r < 4; ++r) { mr[m][r] = -1e30f; sr[m][r] = 0.f; }
  }

  const int nt = (hb + QL + 63) >> 6;
  const int srow = tid >> 4;
  const int seg = tid & 15;

  for (int t = 0; t < nt; ++t) {
    const int kv0 = t << 6;
    __syncthreads();
#pragma unroll
    for (int p = 0; p < 2; ++p) {
      const int row = p * 32 + srow;
      const int kvg = kv0 + row;
      if (kvg < hb) {
        const int blk = bofs[b * 12 + t];
        const size_t base = ((size_t)blk * 64 + (kvg & 63)) * HID + h * HD;
        const float* kf = k_cache + base;
        const float* vf = v_cache + base;
        ushort_t tmp[8];
#pragma unroll
        for (int j = 0; j < 8; ++j) tmp[j] = h2u(f2h(kf[seg * 8 + j]));
        *(s16x8*)&K_lds[row * 136 + seg * 8] = *(s16x8*)tmp;
#pragma unroll
        for (int j = 0; j < 8; ++j) {
          const int d = seg + j * 16;
          V_lds[d * 72 + row] = h2u(f2h(vf[d]));
        }
      } else {
        int r2 = kvg - hb;
        if (r2 > QL - 1) r2 = QL - 1;
        const size_t base = ((size_t)(b * NH + h) * QL + r2) * HD;
        const ushort_t* kb = k_r + base;
        const ushort_t* vb = v_r + base;
        *(s16x8*)&K_lds[row * 136 + seg * 8] = *(const s16x8*)(kb + seg * 8);
#pragma unroll
        for (int j = 0; j < 8; ++j) {
          const int d = seg + j * 16;
          V_lds[d * 72 + row] = vb[d];
        }
      }
    }
    __syncthreads();

    f32x4 sa[2][4];
#pragma unroll
    for (int m = 0; m < 2; ++m)
#pragma unroll
      for (int n = 0; n < 4; ++n) sa[m][n] = (f32x4){0.f, 0.f, 0.f, 0.f};
#pragma unroll
    for (int kd = 0; kd < 4; ++kd) {
      f16x8 kf[4];
#pragma unroll
      for (int n = 0; n < 4; ++n)
        kf[n] = *(const f16x8*)&K_lds[(n * 16 + l16) * 136 + kd * 32 + lg * 8];
#pragma unroll
      for (int m = 0; m < 2; ++m)
#pragma unroll
        for (int n = 0; n < 4; ++n)
          sa[m][n] = MFMA16H(qf[m][kd], kf[n], sa[m][n]);
    }

#pragma unroll
    for (int m = 0; m < 2; ++m) {
#pragma unroll
      for (int n = 0; n < 4; ++n) {
        const int kvg = kv0 + n * 16 + l16;
#pragma unroll
        for (int r = 0; r < 4; ++r) {
          const int qg = hb + w * 32 + m * 16 + lg * 4 + r;
          if (kvg > qg) sa[m][n][r] = -1e30f;
        }
      }
      float tm[4], ts[4];
#pragma unroll
      for (int r = 0; r < 4; ++r)
        tm[r] = fmaxf(fmaxf(sa[m][0][r], sa[m][1][r]),
                      fmaxf(sa[m][2][r], sa[m][3][r]));
#pragma unroll
      for (int x = 1; x < 16; x <<= 1)
#pragma unroll
        for (int r = 0; r < 4; ++r)
          tm[r] = fmaxf(tm[r], __shfl_xor(tm[r], x, 16));
#pragma unroll
      for (int r = 0; r < 4; ++r) {
        const float nm = fmaxf(mr[m][r], tm[r]);
        const float corr = __expf(mr[m][r] - nm);
        mr[m][r] = nm;
        sr[m][r] *= corr;
#pragma unroll
        for (int d = 0; d < 8; ++d) o[m][d][r] *= corr;
        ts[r] = 0.f;
      }
#pragma unroll
      for (int n = 0; n < 4; ++n)
#pragma unroll
        for (int r = 0; r < 4; ++r) {
          const float p = __expf(sa[m][n][r] - mr[m][r]);
          sa[m][n][r] = p;
          ts[r] += p;
        }
#pragma unroll
      for (int x = 1; x < 16; x <<= 1)
#pragma unroll
        for (int r = 0; r < 4; ++r) ts[r] += __shfl_xor(ts[r], x, 16);
#pragma unroll
      for (int r = 0; r < 4; ++r) sr[m][r] += ts[r];
#pragma unroll
      for (int n = 0; n < 4; ++n)
#pragma unroll
        for (int r = 0; r < 4; ++r)
          P_lds[(w * 32 + m * 16 + lg * 4 + r) * 72 + n * 16 + l16] =
              h2u(f2h(sa[m][n][r]));
    }

#pragma unroll
    for (int ks = 0; ks < 2; ++ks) {
      f16x8 pa[2];
#pragma unroll
      for (int m = 0; m < 2; ++m)
        pa[m] = *(const f16x8*)&P_lds[(w * 32 + m * 16 + l16) * 72 + ks * 32 + lg * 8];
#pragma unroll
      for (int d = 0; d < 8; ++d) {
        const f16x8 vb =
            *(const f16x8*)&V_lds[(d * 16 + l16) * 72 + ks * 32 + lg * 8];
#pragma unroll
        for (int m = 0; m < 2; ++m) o[m][d] = MFMA16H(pa[m], vb, o[m][d]);
      }
    }
  }

#pragma unroll
  for (int m = 0; m < 2; ++m)
#pragma unroll
    for (int r = 0; r < 4; ++r) {
      const int qrow = w * 32 + m * 16 + lg * 4 + r;
      const float inv = 1.0f / sr[m][r];
      const size_t obase = ((size_t)(b * QL + qrow)) * HID + h * HD;
#pragma unroll
      for (int d = 0; d < 8; ++d)
        attn_h[obase + d * 16 + l16] = h2u(f2h(o[m][d][r] * inv));
    }
}

// ---------------------------------------------------------------------------
extern "C" void kernel_launch(void* const* d_in, const int* in_sizes, int n_in,
                              void* d_out, int out_size, void* d_ws,
                              size_t ws_size, hipStream_t stream) {
  const float* hidden   = (const float*)d_in[0];  // (1,2048,4096) f32
  const float* c_attn_w = (const float*)d_in[1];  // (12288,4096)
  const float* c_attn_b = (const float*)d_in[2];  // (12288,)
  const float* c_proj_w = (const float*)d_in[3];  // (4096,4096)
  const float* k_cache  = (const float*)d_in[4];  // (96,64,32,128)
  const float* v_cache  = (const float*)d_in[5];
  const int* hist       = (const int*)d_in[6];    // (8,)
  const int* bofs       = (const int*)d_in[7];    // (8,12)
  float* out = (float*)d_out;

  char* ws = (char*)d_ws;
  const size_t MB = 1ull << 20;
  // Region A (0..96MB): w_attn_h (phases 1-3) -> wproj_h (phase 5+)
  ushort_t* w_attn_h = (ushort_t*)(ws);
  ushort_t* wproj_h  = (ushort_t*)(ws);
  // Region B (100..148MB): qkv_h (phases 3-4) -> attn_h (phase 6+)
  ushort_t* qkv_h  = (ushort_t*)(ws + 100 * MB);
  ushort_t* attn_h = (ushort_t*)(ws + 100 * MB);
  // Region C: roped q/k/v (fp16)
  ushort_t* q_r = (ushort_t*)(ws + 148 * MB);
  ushort_t* k_r = (ushort_t*)(ws + 164 * MB);
  ushort_t* v_r = (ushort_t*)(ws + 180 * MB);
  // Region D: x_h
  ushort_t* x_h = (ushort_t*)(ws + 196 * MB);

  // 1) convert inputs for qkv GEMM
  conv_h<<<2048, 256, 0, stream>>>(hidden, x_h, 2048 * 4096 / 8);
  conv_h<<<2048, 256, 0, stream>>>(c_attn_w, w_attn_h, 12288 * 4096 / 8);
  // 2) qkv = x @ c_attn_w^T + b  (fp16 MFMA, fp32 accum)
  gemm_bt<1, 0><<<1536, 256, 0, stream>>>(x_h, w_attn_h, c_attn_b, qkv_h,
                                          nullptr, 12288, 4096);
  // 3) rope + split
  rope_split<<<2048, 256, 0, stream>>>(qkv_h, hist, q_r, k_r, v_r);
  // 4) convert proj weights (overwrites w_attn region; stream-ordered)
  conv_h<<<2048, 256, 0, stream>>>(c_proj_w, wproj_h, 4096 * 4096 / 8);
  // 5) attention -> attn_h (overwrites qkv region; qkv dead after rope)
  attn_fwd<<<256, 512, 0, stream>>>(q_r, k_r, v_r, k_cache, v_cache, hist,
                                    bofs, attn_h);
  // 6) out = attn @ c_proj_w^T (fp16 MFMA, fp32 out)
  gemm_bt<0, 1><<<512, 256, 0, stream>>>(attn_h, wproj_h, nullptr, nullptr,
                                         out, 4096, 4096);
}